// Round 11
// baseline (182.184 us; speedup 1.0000x reference)
//
#include <hip/hip_runtime.h>
#include <math.h>

typedef unsigned short ushort_t;
typedef __bf16 bf16x8 __attribute__((ext_vector_type(8)));
typedef __bf16 bf16x4 __attribute__((ext_vector_type(4)));
typedef float f32x16 __attribute__((ext_vector_type(16)));

#define TWO_PI_F 6.283185307179586f

// ---- ws float-offset layout ----
#define WMT_OFF   0         // [296][512] f32 W_mod^T
#define PC_OFF    151552    // [1024][512] f32 per-b modulation constants
#define WT0P_OFF  675840    // 40960 ushort: GEMM0 W-frags 32x32 [10 ks][8 nt][64 l][8 j]
#define WT1P_OFF  696320    // 98304 ushort: GEMM1 W-frags 32x32 [24 ks][8 nt][64 l][8 j]

__device__ __forceinline__ ushort_t f2bf(float f) {
  unsigned int u = __float_as_uint(f);
  u += 0x7fffu + ((u >> 16) & 1u);
  return (ushort_t)(u >> 16);
}

// ---------------- pack: W_mod^T (f32) + 32x32x16 MFMA A-fragment panels (bf16) ----------------
// A-frag (W as operand A, M=n): row n = nt*32 + (l&31); k = ks*16 + (l>>5)*8 + j.
__global__ void pack_mfma_k(const float* __restrict__ W0,
                            const float* __restrict__ W1,
                            const float* __restrict__ W_mod,
                            float* __restrict__ WmT,
                            ushort_t* __restrict__ WT0p,
                            ushort_t* __restrict__ WT1p) {
  int i0 = blockIdx.x * blockDim.x + threadIdx.x;
  int stride = gridDim.x * blockDim.x;
  for (int idx = i0; idx < 296 * 512; idx += stride) {
    int c = idx >> 9, m = idx & 511;
    WmT[idx] = W_mod[m * 296 + c];
  }
  // GEMM0: K=160 -> 10 k16-steps. k<17: W0; 17..31: 0 (pos pad); 32..159: W_mod[.,128+k-32]
  for (int e = i0; e < 40960; e += stride) {
    int j = e & 7, l = (e >> 3) & 63, nt = (e >> 9) & 7, ks = e >> 12;
    int k = ks * 16 + ((l >> 5) << 3) + j;
    int n = nt * 32 + (l & 31);
    float v = 0.0f;
    if (k < 17) v = W0[n * 17 + k];
    else if (k >= 32) v = W_mod[n * 296 + 128 + (k - 32)];
    WT0p[e] = f2bf(v);
  }
  // GEMM1: K=384 -> 24 k16-steps. k<256: W1; else W_mod[256+n][128+k-256]
  for (int e = i0; e < 98304; e += stride) {
    int j = e & 7, l = (e >> 3) & 63, nt = (e >> 9) & 7, ks = e >> 12;
    int k = ks * 16 + ((l >> 5) << 3) + j;
    int n = nt * 32 + (l & 31);
    float v = (k < 256) ? W1[n * 256 + k]
                        : W_mod[(256 + n) * 296 + 128 + (k - 256)];
    WT1p[e] = f2bf(v);
  }
}

// ---------------- static encoder + per-b modulation consts (verified R1-R10) ----------------
__global__ void precompute_pc_k(const float* __restrict__ code,
                                const float* __restrict__ x_statics,
                                const int* __restrict__ dir_idx,
                                const float* __restrict__ WmT,
                                const float* __restrict__ b_mod,
                                const float* __restrict__ b0,
                                const float* __restrict__ b1,
                                const float* __restrict__ Bmat,
                                const float* __restrict__ Ws1,
                                const float* __restrict__ bs1,
                                const float* __restrict__ Ws2,
                                const float* __restrict__ bs2,
                                const float* __restrict__ dir_emb,
                                float* __restrict__ pc) {
  int b = blockIdx.x, t = threadIdx.x;  // 512 threads
  __shared__ float feats[32];
  __shared__ float h[64];
  __shared__ float se[40];
  __shared__ float cd[128];
  if (t < 16) {
    float p = TWO_PI_F * (x_statics[2 * b] * Bmat[t] + x_statics[2 * b + 1] * Bmat[16 + t]);
    feats[t] = sinf(p);
    feats[16 + t] = cosf(p);
  }
  if (t >= 128 && t < 256) cd[t - 128] = code[b * 128 + (t - 128)];
  __syncthreads();
  if (t < 64) {
    float a = bs1[t];
#pragma unroll
    for (int c = 0; c < 32; ++c) a = fmaf(feats[c], Ws1[t * 32 + c], a);
    h[t] = 0.5f * a * (1.0f + erff(a * 0.70710678118654752440f));
  }
  __syncthreads();
  if (t < 32) {
    float a = bs2[t];
#pragma unroll
    for (int c = 0; c < 64; ++c) a = fmaf(h[c], Ws2[t * 64 + c], a);
    se[t] = a;
  } else if (t < 40) {
    se[t] = dir_emb[dir_idx[b] * 8 + (t - 32)];
  }
  __syncthreads();
  float a = b_mod[t] + ((t < 256) ? b0[t] : b1[t - 256]);
  for (int c = 0; c < 128; ++c) a = fmaf(cd[c], WmT[c * 512 + t], a);
#pragma unroll
  for (int c = 0; c < 40; ++c) a = fmaf(se[c], WmT[(256 + c) * 512 + t], a);
  pc[b * 512 + t] = a;
}

// ---------------- main: MFMA FiLM MLP, 4 waves x (64r x 64c), 32x32x16 ----------------
// R11 vs R10: same geometry/LDS/swizzle, MFMA shape 16x16x32 -> 32x32x16.
// Per k32-step per wave: 16 MFMA -> 8, issue slots 24 -> 16 (we are issue/
// latency-bound: R10 showed all pipes at 33-39%, nothing saturated).
// Wave tile 64x64 = 2x2 tiles of 32x32; acc[2][2] f32x16 = 64 VGPR.
// D[n][t]: t = l&31 (col), n = (r&3) + 8*(r>>2) + 4*(l>>5) (row), r=0..15.
// U (B-op): col t = l&31, k = (l>>5)*8 + j -> 16B ds_read at t*768 + k*2.
// rowbuf row (768B), XOR-swizzle ((t&7)<<4): [0,64) pos (k 0..31, GEMM0 steps
// 0,1 read LAST), [0,512) x0 after epilogue0, [512,768) hs.
__global__ __launch_bounds__(256, 3) void film_mfma(
    const float* __restrict__ coords, const float* __restrict__ hs,
    const float* __restrict__ pc, const ushort_t* __restrict__ WT0p,
    const ushort_t* __restrict__ WT1p, const float* __restrict__ Wo,
    const float* __restrict__ bo, float* __restrict__ out) {
  __shared__ uint4 rowbuf4[49152 / 16];
  __shared__ float pcs[512];
  __shared__ float psum[256];  // [wc 4][row 64]
  char* rowbuf = (char*)rowbuf4;

  const int tid = threadIdx.x;
  const int wc = tid >> 6;
  const int l = tid & 63;
  const int l31 = l & 31;
  const int h = l >> 5;
  const size_t row0 = (size_t)blockIdx.x * 64;
  const int b = blockIdx.x >> 3;

  pcs[tid] = pc[(size_t)b * 512 + tid];
  pcs[tid + 256] = pc[(size_t)b * 512 + 256 + tid];

  // ---- stage hs -> rowbuf[row][512..768), bf16, swizzled ----
  {
    const float4* hsv = (const float4*)(hs + row0 * 128);
#pragma unroll
    for (int it = 0; it < 8; ++it) {
      int idx = it * 256 + tid;   // 2048 float4 = 64 rows x 32
      int r = idx >> 5, c4 = idx & 31;
      float4 v = hsv[idx];
      bf16x4 hb;
      hb[0] = (__bf16)v.x; hb[1] = (__bf16)v.y;
      hb[2] = (__bf16)v.z; hb[3] = (__bf16)v.w;
      int byte = (r * 768 + 512 + c4 * 8) ^ ((r & 7) << 4);
      *(uint2*)(rowbuf + byte) = __builtin_bit_cast(uint2, hb);
    }
  }
  // ---- stage pos -> rowbuf[row][0..64), bf16, pre-swizzled 16B chunks ----
  if (tid < 64) {
    int row = tid;
    float c = coords[row0 + row];
    __bf16 pv[32];
    pv[0] = (__bf16)c;
    pv[1] = (__bf16)0.0f;  // sin(0*c)
    pv[9] = (__bf16)1.0f;  // cos(0*c)
#pragma unroll
    for (int f = 1; f < 8; ++f) {
      float s, co;
      __sincosf(1.25f * (float)f * c, &s, &co);
      pv[1 + f] = (__bf16)s;
      pv[9 + f] = (__bf16)co;
    }
#pragma unroll
    for (int k = 17; k < 32; ++k) pv[k] = (__bf16)0.0f;
    int base = row * 768, swzp = (row & 7) << 4;
#pragma unroll
    for (int s = 0; s < 4; ++s)
      *(uint4*)(rowbuf + ((base + s * 16) ^ swzp)) = *(const uint4*)&pv[s * 8];
  }

  // U addressing: t = mt*32 + l31 -> t&7 == l&7 for both mt
  const int swzU = (l & 7) << 4;
  int addrU[2];
#pragma unroll
  for (int mt = 0; mt < 2; ++mt)
    addrU[mt] = (mt * 32 + l31) * 768 + h * 16;

  const uint4* Bb0 = (const uint4*)WT0p;
  const uint4* Bb1 = (const uint4*)WT1p;

  // GEMM0 k16-step order: {2..9, 0, 1} (pos steps 0,1 last)
  constexpr int ord0[10] = {2, 3, 4, 5, 6, 7, 8, 9, 0, 1};

  // prefetch first step's W frags before the staging barrier
  uint4 wp0 = Bb0[(2 * 8 + wc * 2 + 0) * 64 + l];
  uint4 wp1 = Bb0[(2 * 8 + wc * 2 + 1) * 64 + l];

  __syncthreads();

  f32x16 acc[2][2];
#pragma unroll
  for (int mt = 0; mt < 2; ++mt)
#pragma unroll
    for (int nt = 0; nt < 2; ++nt)
#pragma unroll
      for (int q = 0; q < 16; ++q) acc[mt][nt][q] = 0.f;

  // ---------------- GEMM0: K=160, 10 k16-steps, W double-buffered ----------------
#pragma unroll
  for (int kk = 0; kk < 10; ++kk) {
    const int s = ord0[kk];
    bf16x8 w0 = __builtin_bit_cast(bf16x8, wp0);
    bf16x8 w1 = __builtin_bit_cast(bf16x8, wp1);
    if (kk < 9) {
      const int sn = ord0[kk + 1];
      wp0 = Bb0[(sn * 8 + wc * 2 + 0) * 64 + l];
      wp1 = Bb0[(sn * 8 + wc * 2 + 1) * 64 + l];
    }
    const int kb = (s < 2) ? s * 32 : 448 + s * 32;  // pos at [0,64), hs at [512,768)
    bf16x8 u0, u1;
    __builtin_memcpy(&u0, rowbuf + ((addrU[0] + kb) ^ swzU), 16);
    __builtin_memcpy(&u1, rowbuf + ((addrU[1] + kb) ^ swzU), 16);
    acc[0][0] = __builtin_amdgcn_mfma_f32_32x32x16_bf16(w0, u0, acc[0][0], 0, 0, 0);
    acc[0][1] = __builtin_amdgcn_mfma_f32_32x32x16_bf16(w1, u0, acc[0][1], 0, 0, 0);
    acc[1][0] = __builtin_amdgcn_mfma_f32_32x32x16_bf16(w0, u1, acc[1][0], 0, 0, 0);
    acc[1][1] = __builtin_amdgcn_mfma_f32_32x32x16_bf16(w1, u1, acc[1][1], 0, 0, 0);
  }

  // prefetch GEMM1 step 0 weights; they land during epilogue0 + barriers
  wp0 = Bb1[(0 * 8 + wc * 2 + 0) * 64 + l];
  wp1 = Bb1[(0 * 8 + wc * 2 + 1) * 64 + l];

  __syncthreads();  // all pos reads done before x0 overwrites [0,512)

  // ---- epilogue0: relu(acc + pc0) -> x0 bf16, packed b64 writes ----
  // lane covers n = wc*64 + nt*32 + h*4 + g*8 + (0..3), t = mt*32 + l31
#pragma unroll
  for (int mt = 0; mt < 2; ++mt) {
    const int tb = (mt * 32 + l31) * 768;
#pragma unroll
    for (int nt = 0; nt < 2; ++nt) {
#pragma unroll
      for (int g = 0; g < 4; ++g) {
        int n0 = wc * 64 + nt * 32 + h * 4 + g * 8;
        float4 p4 = *(const float4*)&pcs[n0];
        bf16x4 hv;
        hv[0] = (__bf16)fmaxf(acc[mt][nt][g * 4 + 0] + p4.x, 0.f);
        hv[1] = (__bf16)fmaxf(acc[mt][nt][g * 4 + 1] + p4.y, 0.f);
        hv[2] = (__bf16)fmaxf(acc[mt][nt][g * 4 + 2] + p4.z, 0.f);
        hv[3] = (__bf16)fmaxf(acc[mt][nt][g * 4 + 3] + p4.w, 0.f);
        *(uint2*)(rowbuf + ((tb + n0 * 2) ^ swzU)) = __builtin_bit_cast(uint2, hv);
      }
    }
  }
  __syncthreads();

#pragma unroll
  for (int mt = 0; mt < 2; ++mt)
#pragma unroll
    for (int nt = 0; nt < 2; ++nt)
#pragma unroll
      for (int q = 0; q < 16; ++q) acc[mt][nt][q] = 0.f;

  // ---------------- GEMM1: K=384, 24 k16-steps (x0 then hs, contiguous) ----------------
#pragma unroll
  for (int s = 0; s < 24; ++s) {
    bf16x8 w0 = __builtin_bit_cast(bf16x8, wp0);
    bf16x8 w1 = __builtin_bit_cast(bf16x8, wp1);
    if (s < 23) {
      wp0 = Bb1[((s + 1) * 8 + wc * 2 + 0) * 64 + l];
      wp1 = Bb1[((s + 1) * 8 + wc * 2 + 1) * 64 + l];
    }
    const int kb = s * 32;
    bf16x8 u0, u1;
    __builtin_memcpy(&u0, rowbuf + ((addrU[0] + kb) ^ swzU), 16);
    __builtin_memcpy(&u1, rowbuf + ((addrU[1] + kb) ^ swzU), 16);
    acc[0][0] = __builtin_amdgcn_mfma_f32_32x32x16_bf16(w0, u0, acc[0][0], 0, 0, 0);
    acc[0][1] = __builtin_amdgcn_mfma_f32_32x32x16_bf16(w1, u0, acc[0][1], 0, 0, 0);
    acc[1][0] = __builtin_amdgcn_mfma_f32_32x32x16_bf16(w0, u1, acc[1][0], 0, 0, 0);
    acc[1][1] = __builtin_amdgcn_mfma_f32_32x32x16_bf16(w1, u1, acc[1][1], 0, 0, 0);
  }

  // ---- epilogue1: relu(acc + pc1) . Wo; 16 n per lane-half + shfl(32) -> psum ----
#pragma unroll
  for (int mt = 0; mt < 2; ++mt) {
    float s = 0.f;
#pragma unroll
    for (int nt = 0; nt < 2; ++nt) {
#pragma unroll
      for (int g = 0; g < 4; ++g) {
        int n0 = wc * 64 + nt * 32 + h * 4 + g * 8;
        float4 p4 = *(const float4*)&pcs[256 + n0];
        float4 w4 = ((const float4*)Wo)[n0 >> 2];
        s += fmaxf(acc[mt][nt][g * 4 + 0] + p4.x, 0.f) * w4.x;
        s += fmaxf(acc[mt][nt][g * 4 + 1] + p4.y, 0.f) * w4.y;
        s += fmaxf(acc[mt][nt][g * 4 + 2] + p4.z, 0.f) * w4.z;
        s += fmaxf(acc[mt][nt][g * 4 + 3] + p4.w, 0.f) * w4.w;
      }
    }
    s += __shfl_xor(s, 32);
    if (l < 32) psum[wc * 64 + mt * 32 + l31] = s;
  }
  __syncthreads();
  if (tid < 64) {
    float s = bo[0] + psum[tid] + psum[64 + tid] + psum[128 + tid] + psum[192 + tid];
    out[row0 + tid] = s;
  }
}

extern "C" void kernel_launch(void* const* d_in, const int* in_sizes, int n_in,
                              void* d_out, int out_size, void* d_ws, size_t ws_size,
                              hipStream_t stream) {
  (void)in_sizes; (void)n_in; (void)out_size; (void)ws_size;
  const float* coords    = (const float*)d_in[0];
  const float* code      = (const float*)d_in[1];
  const float* hs        = (const float*)d_in[2];
  const float* x_statics = (const float*)d_in[3];
  const int*   dir_idx   = (const int*)d_in[4];
  const float* W_mod     = (const float*)d_in[5];
  const float* b_mod     = (const float*)d_in[6];
  const float* W0        = (const float*)d_in[7];
  const float* b0        = (const float*)d_in[8];
  const float* W1        = (const float*)d_in[9];
  const float* b1        = (const float*)d_in[10];
  const float* Wo        = (const float*)d_in[11];
  const float* bo        = (const float*)d_in[12];
  const float* Bmat      = (const float*)d_in[13];
  const float* Ws1       = (const float*)d_in[14];
  const float* bs1       = (const float*)d_in[15];
  const float* Ws2       = (const float*)d_in[16];
  const float* bs2       = (const float*)d_in[17];
  const float* dir_emb   = (const float*)d_in[18];
  float* out = (float*)d_out;
  float* wsf = (float*)d_ws;

  float*    WmT  = wsf + WMT_OFF;
  float*    pc   = wsf + PC_OFF;
  ushort_t* WT0p = (ushort_t*)(wsf + WT0P_OFF);
  ushort_t* WT1p = (ushort_t*)(wsf + WT1P_OFF);

  hipLaunchKernelGGL(pack_mfma_k, dim3(1024), dim3(256), 0, stream,
                     W0, W1, W_mod, WmT, WT0p, WT1p);
  hipLaunchKernelGGL(precompute_pc_k, dim3(1024), dim3(512), 0, stream,
                     code, x_statics, dir_idx, WmT, b_mod, b0, b1,
                     Bmat, Ws1, bs1, Ws2, bs2, dir_emb, pc);
  hipLaunchKernelGGL(film_mfma, dim3(8192), dim3(256), 0, stream,
                     coords, hs, pc, WT0p, WT1p, Wo, bo, out);
}

// Round 12
// 178.472 us; speedup vs baseline: 1.0208x; 1.0208x over previous
//
#include <hip/hip_runtime.h>
#include <math.h>

typedef unsigned short ushort_t;
typedef __bf16 bf16x8 __attribute__((ext_vector_type(8)));
typedef __bf16 bf16x4 __attribute__((ext_vector_type(4)));
typedef float f32x4 __attribute__((ext_vector_type(4)));

#define TWO_PI_F 6.283185307179586f

// ---- ws float-offset layout ----
#define WMT_OFF   0         // [296][512] f32 W_mod^T
#define PC_OFF    151552    // [1024][512] f32 per-b modulation constants
#define WT0P_OFF  675840    // 40960 ushort: GEMM0 W-frags [5 ks][16 nt][64 l][8 j]
#define WT1P_OFF  696320    // 98304 ushort: GEMM1 W-frags [12 ks][16 nt][64 l][8 j]

__device__ __forceinline__ ushort_t f2bf(float f) {
  unsigned int u = __float_as_uint(f);
  u += 0x7fffu + ((u >> 16) & 1u);
  return (ushort_t)(u >> 16);
}

// ---------------- pack: W_mod^T (f32) + MFMA W-fragment panels (bf16) ----------------
__global__ void pack_mfma_k(const float* __restrict__ W0,
                            const float* __restrict__ W1,
                            const float* __restrict__ W_mod,
                            float* __restrict__ WmT,
                            ushort_t* __restrict__ WT0p,
                            ushort_t* __restrict__ WT1p) {
  int i0 = blockIdx.x * blockDim.x + threadIdx.x;
  int stride = gridDim.x * blockDim.x;
  for (int idx = i0; idx < 296 * 512; idx += stride) {
    int c = idx >> 9, m = idx & 511;
    WmT[idx] = W_mod[m * 296 + c];
  }
  for (int e = i0; e < 40960; e += stride) {
    int j = e & 7, l = (e >> 3) & 63, nt = (e >> 9) & 15, ks = e >> 13;
    int k = ks * 32 + (l >> 4) * 8 + j;
    int n = nt * 16 + (l & 15);
    float v = 0.0f;
    if (k < 17) v = W0[n * 17 + k];
    else if (k >= 32) v = W_mod[n * 296 + 128 + (k - 32)];
    WT0p[e] = f2bf(v);
  }
  for (int e = i0; e < 98304; e += stride) {
    int j = e & 7, l = (e >> 3) & 63, nt = (e >> 9) & 15, ks = e >> 13;
    int k = ks * 32 + (l >> 4) * 8 + j;
    int n = nt * 16 + (l & 15);
    float v = (k < 256) ? W1[n * 256 + k]
                        : W_mod[(256 + n) * 296 + 128 + (k - 256)];
    WT1p[e] = f2bf(v);
  }
}

// ---------------- static encoder + per-b modulation consts (verified R1-R11) ----------------
__global__ void precompute_pc_k(const float* __restrict__ code,
                                const float* __restrict__ x_statics,
                                const int* __restrict__ dir_idx,
                                const float* __restrict__ WmT,
                                const float* __restrict__ b_mod,
                                const float* __restrict__ b0,
                                const float* __restrict__ b1,
                                const float* __restrict__ Bmat,
                                const float* __restrict__ Ws1,
                                const float* __restrict__ bs1,
                                const float* __restrict__ Ws2,
                                const float* __restrict__ bs2,
                                const float* __restrict__ dir_emb,
                                float* __restrict__ pc) {
  int b = blockIdx.x, t = threadIdx.x;  // 512 threads
  __shared__ float feats[32];
  __shared__ float h[64];
  __shared__ float se[40];
  __shared__ float cd[128];
  if (t < 16) {
    float p = TWO_PI_F * (x_statics[2 * b] * Bmat[t] + x_statics[2 * b + 1] * Bmat[16 + t]);
    feats[t] = sinf(p);
    feats[16 + t] = cosf(p);
  }
  if (t >= 128 && t < 256) cd[t - 128] = code[b * 128 + (t - 128)];
  __syncthreads();
  if (t < 64) {
    float a = bs1[t];
#pragma unroll
    for (int c = 0; c < 32; ++c) a = fmaf(feats[c], Ws1[t * 32 + c], a);
    h[t] = 0.5f * a * (1.0f + erff(a * 0.70710678118654752440f));
  }
  __syncthreads();
  if (t < 32) {
    float a = bs2[t];
#pragma unroll
    for (int c = 0; c < 64; ++c) a = fmaf(h[c], Ws2[t * 64 + c], a);
    se[t] = a;
  } else if (t < 40) {
    se[t] = dir_emb[dir_idx[b] * 8 + (t - 32)];
  }
  __syncthreads();
  float a = b_mod[t] + ((t < 256) ? b0[t] : b1[t - 256]);
  for (int c = 0; c < 128; ++c) a = fmaf(cd[c], WmT[c * 512 + t], a);
#pragma unroll
  for (int c = 0; c < 40; ++c) a = fmaf(se[c], WmT[(256 + c) * 512 + t], a);
  pc[b * 512 + t] = a;
}

// ---------------- main: MFMA FiLM MLP, 4 waves x (64r x 64c) ----------------
// R12 = R10 (166us best) + (a) u-fragment register double-buffer so the MFMA
// cluster never waits on lgkm (we are latency-bound: all pipes 33-40%, 3
// waves/SIMD), + (b) s_setprio(1) around the MFMA cluster (T5; phase-skewed
// co-resident blocks give the scheduler role diversity).
// grid = 8192 (64 rows), block = 256 = 4 waves; wave wc owns n-cols
// [wc*64, wc*64+64) via 4 W-frags; mt 0..3 covers the 64 t-rows.
// LDS 51.2 KB -> 3 blocks/CU; (256,3) -> 170-reg cap (demand ~130, no spill).
// rowbuf row (768B), XOR-swizzle ((row&7)<<4) on 16B chunks:
//   GEMM0 k-order {1,2,3,4,0}: pos (bytes [0,64)) read last; barrier;
//   epilogue0 overwrites [0,512) with x0; GEMM1 reads ks*64, ks=0..11.
__global__ __launch_bounds__(256, 3) void film_mfma(
    const float* __restrict__ coords, const float* __restrict__ hs,
    const float* __restrict__ pc, const ushort_t* __restrict__ WT0p,
    const ushort_t* __restrict__ WT1p, const float* __restrict__ Wo,
    const float* __restrict__ bo, float* __restrict__ out) {
  __shared__ uint4 rowbuf4[49152 / 16];
  __shared__ float pcs[512];
  __shared__ float psum[256];  // [wc 4][row 64]
  char* rowbuf = (char*)rowbuf4;

  const int tid = threadIdx.x;
  const int wc = tid >> 6;
  const int l = tid & 63;
  const int l4 = l & 15;
  const int hi4 = l >> 4;
  const size_t row0 = (size_t)blockIdx.x * 64;
  const int b = blockIdx.x >> 3;

  pcs[tid] = pc[(size_t)b * 512 + tid];
  pcs[tid + 256] = pc[(size_t)b * 512 + 256 + tid];

  // ---- stage hs -> rowbuf[row][512..768), bf16, swizzled ----
  {
    const float4* hsv = (const float4*)(hs + row0 * 128);
#pragma unroll
    for (int it = 0; it < 8; ++it) {
      int idx = it * 256 + tid;   // 2048 float4 = 64 rows x 32
      int r = idx >> 5, c4 = idx & 31;
      float4 v = hsv[idx];
      bf16x4 hb;
      hb[0] = (__bf16)v.x; hb[1] = (__bf16)v.y;
      hb[2] = (__bf16)v.z; hb[3] = (__bf16)v.w;
      int byte = (r * 768 + 512 + c4 * 8) ^ ((r & 7) << 4);
      *(uint2*)(rowbuf + byte) = __builtin_bit_cast(uint2, hb);
    }
  }
  // ---- stage pos -> rowbuf[row][0..64), bf16, pre-swizzled 16B chunks ----
  if (tid < 64) {
    int row = tid;
    float c = coords[row0 + row];
    __bf16 pv[32];
    pv[0] = (__bf16)c;
    pv[1] = (__bf16)0.0f;  // sin(0*c)
    pv[9] = (__bf16)1.0f;  // cos(0*c)
#pragma unroll
    for (int f = 1; f < 8; ++f) {
      float s, co;
      __sincosf(1.25f * (float)f * c, &s, &co);
      pv[1 + f] = (__bf16)s;
      pv[9 + f] = (__bf16)co;
    }
#pragma unroll
    for (int k = 17; k < 32; ++k) pv[k] = (__bf16)0.0f;
    int base = row * 768, swzp = (row & 7) << 4;
#pragma unroll
    for (int s = 0; s < 4; ++s)
      *(uint4*)(rowbuf + ((base + s * 16) ^ swzp)) = *(const uint4*)&pv[s * 8];
  }

  // per-mt LDS addressing (row&7 == l4&7 since mt*16 ≡ 0 mod 8)
  const int swzU = (l4 & 7) << 4;
  int addrU[4];
#pragma unroll
  for (int mt = 0; mt < 4; ++mt)
    addrU[mt] = (mt * 16 + l4) * 768 + hi4 * 16;

  const uint4* Bb0 = (const uint4*)WT0p;
  const uint4* Bb1 = (const uint4*)WT1p;

  // prefetch GEMM0 step 0 (ks=1) weight frags before the staging barrier
  uint4 wp[4];
#pragma unroll
  for (int i = 0; i < 4; ++i) wp[i] = Bb0[(1 * 16 + wc * 4 + i) * 64 + l];

  __syncthreads();

  f32x4 acc[4][4];
#pragma unroll
  for (int mt = 0; mt < 4; ++mt)
#pragma unroll
    for (int i = 0; i < 4; ++i) acc[mt][i] = (f32x4){0.f, 0.f, 0.f, 0.f};

  // ---------------- GEMM0: K=160, k-order {1,2,3,4,0}, W+U double-buffered ----------------
  {
    bf16x8 ucur[4], unxt[4];
#pragma unroll
    for (int mt = 0; mt < 4; ++mt)  // preload step kk=0 (ks=1 -> hs chunk 0)
      __builtin_memcpy(&ucur[mt], rowbuf + ((addrU[mt] + 512) ^ swzU), 16);

#pragma unroll
    for (int kk = 0; kk < 5; ++kk) {
      bf16x8 w[4];
#pragma unroll
      for (int i = 0; i < 4; ++i) w[i] = __builtin_bit_cast(bf16x8, wp[i]);
      if (kk < 4) {
        const int ksn = (kk < 3) ? (kk + 2) : 0;  // next step's k-chunk
#pragma unroll
        for (int i = 0; i < 4; ++i) wp[i] = Bb0[(ksn * 16 + wc * 4 + i) * 64 + l];
#pragma unroll
        for (int mt = 0; mt < 4; ++mt) {
          int offn = (ksn == 0) ? addrU[mt] : (addrU[mt] + 512 + (ksn - 1) * 64);
          __builtin_memcpy(&unxt[mt], rowbuf + (offn ^ swzU), 16);
        }
      }
      __builtin_amdgcn_s_setprio(1);
#pragma unroll
      for (int mt = 0; mt < 4; ++mt)
#pragma unroll
        for (int i = 0; i < 4; ++i)
          acc[mt][i] = __builtin_amdgcn_mfma_f32_16x16x32_bf16(w[i], ucur[mt], acc[mt][i], 0, 0, 0);
      __builtin_amdgcn_s_setprio(0);
#pragma unroll
      for (int mt = 0; mt < 4; ++mt) ucur[mt] = unxt[mt];
    }
  }

  // prefetch GEMM1 step 0 weights; they land during epilogue0 + barriers
#pragma unroll
  for (int i = 0; i < 4; ++i) wp[i] = Bb1[(wc * 4 + i) * 64 + l];

  __syncthreads();  // all pos reads done before x0 overwrites [0,512)

  // ---- epilogue0: relu(acc + pc0) -> x0 bf16, packed b64 writes ----
#pragma unroll
  for (int i = 0; i < 4; ++i) {
    int n0 = (wc * 4 + i) * 16 + hi4 * 4;
    float4 p4 = *(const float4*)&pcs[n0];
#pragma unroll
    for (int mt = 0; mt < 4; ++mt) {
      int t = mt * 16 + l4;
      bf16x4 hv;
      hv[0] = (__bf16)fmaxf(acc[mt][i][0] + p4.x, 0.f);
      hv[1] = (__bf16)fmaxf(acc[mt][i][1] + p4.y, 0.f);
      hv[2] = (__bf16)fmaxf(acc[mt][i][2] + p4.z, 0.f);
      hv[3] = (__bf16)fmaxf(acc[mt][i][3] + p4.w, 0.f);
      int byte = (t * 768 + n0 * 2) ^ ((t & 7) << 4);
      *(uint2*)(rowbuf + byte) = __builtin_bit_cast(uint2, hv);
    }
  }
  __syncthreads();

#pragma unroll
  for (int mt = 0; mt < 4; ++mt)
#pragma unroll
    for (int i = 0; i < 4; ++i) acc[mt][i] = (f32x4){0.f, 0.f, 0.f, 0.f};

  // ---------------- GEMM1: K=384 (x0 [0,512) then hs [512,768)), W+U double-buffered ----------------
  {
    bf16x8 ucur[4], unxt[4];
#pragma unroll
    for (int mt = 0; mt < 4; ++mt)  // preload ks=0 (x0 chunk 0; valid after barrier)
      __builtin_memcpy(&ucur[mt], rowbuf + (addrU[mt] ^ swzU), 16);

#pragma unroll
    for (int ks = 0; ks < 12; ++ks) {
      bf16x8 w[4];
#pragma unroll
      for (int i = 0; i < 4; ++i) w[i] = __builtin_bit_cast(bf16x8, wp[i]);
      if (ks < 11) {
#pragma unroll
        for (int i = 0; i < 4; ++i) wp[i] = Bb1[((ks + 1) * 16 + wc * 4 + i) * 64 + l];
#pragma unroll
        for (int mt = 0; mt < 4; ++mt)
          __builtin_memcpy(&unxt[mt], rowbuf + ((addrU[mt] + (ks + 1) * 64) ^ swzU), 16);
      }
      __builtin_amdgcn_s_setprio(1);
#pragma unroll
      for (int mt = 0; mt < 4; ++mt)
#pragma unroll
        for (int i = 0; i < 4; ++i)
          acc[mt][i] = __builtin_amdgcn_mfma_f32_16x16x32_bf16(w[i], ucur[mt], acc[mt][i], 0, 0, 0);
      __builtin_amdgcn_s_setprio(0);
#pragma unroll
      for (int mt = 0; mt < 4; ++mt) ucur[mt] = unxt[mt];
    }
  }

  // ---- epilogue1: relu(acc + pc1) . Wo; reduce 16 n per lane + 2 shfl -> psum ----
  {
    float4 p4[4], w4[4];
#pragma unroll
    for (int i = 0; i < 4; ++i) {
      int n0 = (wc * 4 + i) * 16 + hi4 * 4;
      p4[i] = *(const float4*)&pcs[256 + n0];
      w4[i] = ((const float4*)Wo)[(wc * 4 + i) * 4 + hi4];
    }
#pragma unroll
    for (int mt = 0; mt < 4; ++mt) {
      float s = 0.f;
#pragma unroll
      for (int i = 0; i < 4; ++i) {
        s += fmaxf(acc[mt][i][0] + p4[i].x, 0.f) * w4[i].x;
        s += fmaxf(acc[mt][i][1] + p4[i].y, 0.f) * w4[i].y;
        s += fmaxf(acc[mt][i][2] + p4[i].z, 0.f) * w4[i].z;
        s += fmaxf(acc[mt][i][3] + p4[i].w, 0.f) * w4[i].w;
      }
      s += __shfl_xor(s, 16);
      s += __shfl_xor(s, 32);
      if (hi4 == 0) psum[wc * 64 + mt * 16 + l4] = s;
    }
  }
  __syncthreads();
  if (tid < 64) {
    float s = bo[0] + psum[tid] + psum[64 + tid] + psum[128 + tid] + psum[192 + tid];
    out[row0 + tid] = s;
  }
}

extern "C" void kernel_launch(void* const* d_in, const int* in_sizes, int n_in,
                              void* d_out, int out_size, void* d_ws, size_t ws_size,
                              hipStream_t stream) {
  (void)in_sizes; (void)n_in; (void)out_size; (void)ws_size;
  const float* coords    = (const float*)d_in[0];
  const float* code      = (const float*)d_in[1];
  const float* hs        = (const float*)d_in[2];
  const float* x_statics = (const float*)d_in[3];
  const int*   dir_idx   = (const int*)d_in[4];
  const float* W_mod     = (const float*)d_in[5];
  const float* b_mod     = (const float*)d_in[6];
  const float* W0        = (const float*)d_in[7];
  const float* b0        = (const float*)d_in[8];
  const float* W1        = (const float*)d_in[9];
  const float* b1        = (const float*)d_in[10];
  const float* Wo        = (const float*)d_in[11];
  const float* bo        = (const float*)d_in[12];
  const float* Bmat      = (const float*)d_in[13];
  const float* Ws1       = (const float*)d_in[14];
  const float* bs1       = (const float*)d_in[15];
  const float* Ws2       = (const float*)d_in[16];
  const float* bs2       = (const float*)d_in[17];
  const float* dir_emb   = (const float*)d_in[18];
  float* out = (float*)d_out;
  float* wsf = (float*)d_ws;

  float*    WmT  = wsf + WMT_OFF;
  float*    pc   = wsf + PC_OFF;
  ushort_t* WT0p = (ushort_t*)(wsf + WT0P_OFF);
  ushort_t* WT1p = (ushort_t*)(wsf + WT1P_OFF);

  hipLaunchKernelGGL(pack_mfma_k, dim3(1024), dim3(256), 0, stream,
                     W0, W1, W_mod, WmT, WT0p, WT1p);
  hipLaunchKernelGGL(precompute_pc_k, dim3(1024), dim3(512), 0, stream,
                     code, x_statics, dir_idx, WmT, b_mod, b0, b1,
                     Bmat, Ws1, bs1, Ws2, bs2, dir_emb, pc);
  hipLaunchKernelGGL(film_mfma, dim3(8192), dim3(256), 0, stream,
                     coords, hs, pc, WT0p, WT1p, Wo, bo, out);
}

// Round 13
// 163.882 us; speedup vs baseline: 1.1117x; 1.0890x over previous
//
#include <hip/hip_runtime.h>
#include <math.h>

typedef unsigned short ushort_t;
typedef __bf16 bf16x8 __attribute__((ext_vector_type(8)));
typedef __bf16 bf16x4 __attribute__((ext_vector_type(4)));
typedef float f32x4 __attribute__((ext_vector_type(4)));

#define TWO_PI_F 6.283185307179586f

// ---- ws float-offset layout ----
#define WMT_OFF   0         // [296][512] f32 W_mod^T
#define PC_OFF    151552    // [1024][512] f32 per-b modulation constants
#define WT0P_OFF  675840    // 40960 ushort: GEMM0 W-frags [5 ks][16 nt][64 l][8 j]
#define WT1P_OFF  696320    // 98304 ushort: GEMM1 W-frags [12 ks][16 nt][64 l][8 j]

__device__ __forceinline__ ushort_t f2bf(float f) {
  unsigned int u = __float_as_uint(f);
  u += 0x7fffu + ((u >> 16) & 1u);
  return (ushort_t)(u >> 16);
}

// ---------------- pack: W_mod^T (f32) + MFMA W-fragment panels (bf16) ----------------
__global__ void pack_mfma_k(const float* __restrict__ W0,
                            const float* __restrict__ W1,
                            const float* __restrict__ W_mod,
                            float* __restrict__ WmT,
                            ushort_t* __restrict__ WT0p,
                            ushort_t* __restrict__ WT1p) {
  int i0 = blockIdx.x * blockDim.x + threadIdx.x;
  int stride = gridDim.x * blockDim.x;
  for (int idx = i0; idx < 296 * 512; idx += stride) {
    int c = idx >> 9, m = idx & 511;
    WmT[idx] = W_mod[m * 296 + c];
  }
  for (int e = i0; e < 40960; e += stride) {
    int j = e & 7, l = (e >> 3) & 63, nt = (e >> 9) & 15, ks = e >> 13;
    int k = ks * 32 + (l >> 4) * 8 + j;
    int n = nt * 16 + (l & 15);
    float v = 0.0f;
    if (k < 17) v = W0[n * 17 + k];
    else if (k >= 32) v = W_mod[n * 296 + 128 + (k - 32)];
    WT0p[e] = f2bf(v);
  }
  for (int e = i0; e < 98304; e += stride) {
    int j = e & 7, l = (e >> 3) & 63, nt = (e >> 9) & 15, ks = e >> 13;
    int k = ks * 32 + (l >> 4) * 8 + j;
    int n = nt * 16 + (l & 15);
    float v = (k < 256) ? W1[n * 256 + k]
                        : W_mod[(256 + n) * 296 + 128 + (k - 256)];
    WT1p[e] = f2bf(v);
  }
}

// ---------------- static encoder + per-b modulation consts (verified R1-R12) ----------------
__global__ void precompute_pc_k(const float* __restrict__ code,
                                const float* __restrict__ x_statics,
                                const int* __restrict__ dir_idx,
                                const float* __restrict__ WmT,
                                const float* __restrict__ b_mod,
                                const float* __restrict__ b0,
                                const float* __restrict__ b1,
                                const float* __restrict__ Bmat,
                                const float* __restrict__ Ws1,
                                const float* __restrict__ bs1,
                                const float* __restrict__ Ws2,
                                const float* __restrict__ bs2,
                                const float* __restrict__ dir_emb,
                                float* __restrict__ pc) {
  int b = blockIdx.x, t = threadIdx.x;  // 512 threads
  __shared__ float feats[32];
  __shared__ float h[64];
  __shared__ float se[40];
  __shared__ float cd[128];
  if (t < 16) {
    float p = TWO_PI_F * (x_statics[2 * b] * Bmat[t] + x_statics[2 * b + 1] * Bmat[16 + t]);
    feats[t] = sinf(p);
    feats[16 + t] = cosf(p);
  }
  if (t >= 128 && t < 256) cd[t - 128] = code[b * 128 + (t - 128)];
  __syncthreads();
  if (t < 64) {
    float a = bs1[t];
#pragma unroll
    for (int c = 0; c < 32; ++c) a = fmaf(feats[c], Ws1[t * 32 + c], a);
    h[t] = 0.5f * a * (1.0f + erff(a * 0.70710678118654752440f));
  }
  __syncthreads();
  if (t < 32) {
    float a = bs2[t];
#pragma unroll
    for (int c = 0; c < 64; ++c) a = fmaf(h[c], Ws2[t * 64 + c], a);
    se[t] = a;
  } else if (t < 40) {
    se[t] = dir_emb[dir_idx[b] * 8 + (t - 32)];
  }
  __syncthreads();
  float a = b_mod[t] + ((t < 256) ? b0[t] : b1[t - 256]);
  for (int c = 0; c < 128; ++c) a = fmaf(cd[c], WmT[c * 512 + t], a);
#pragma unroll
  for (int c = 0; c < 40; ++c) a = fmaf(se[c], WmT[(256 + c) * 512 + t], a);
  pc[b * 512 + t] = a;
}

// ---------------- main: MFMA FiLM MLP, 4 waves x (64r x 64c) ----------------
// R13 = R10 (166us best) byte-exact + s_setprio(1)/(0) around the MFMA
// clusters ONLY (T5, isolated; R12 bundled it with a u-dbuf that spilled).
// grid = 8192 (64 rows), block = 256 = 4 waves; wave wc owns n-cols
// [wc*64, wc*64+64) via 4 W-frags; mt 0..3 covers the 64 t-rows.
// LDS 52224 -> 3 blocks/CU (12 waves, phase-skewed -> setprio has role
// diversity to arbitrate). (256,3) -> 170-reg cap; R10 measured 84, no spill.
// rowbuf row (768B), XOR-swizzle ((row&7)<<4) on 16B chunks:
//   GEMM0 k-order {1,2,3,4,0}: pos (bytes [0,64)) read last; barrier;
//   epilogue0 overwrites [0,512) with x0; GEMM1 reads ks*64, ks=0..11.
__global__ __launch_bounds__(256, 3) void film_mfma(
    const float* __restrict__ coords, const float* __restrict__ hs,
    const float* __restrict__ pc, const ushort_t* __restrict__ WT0p,
    const ushort_t* __restrict__ WT1p, const float* __restrict__ Wo,
    const float* __restrict__ bo, float* __restrict__ out) {
  __shared__ uint4 rowbuf4[49152 / 16];
  __shared__ float pcs[512];
  __shared__ float psum[256];  // [wc 4][row 64]
  char* rowbuf = (char*)rowbuf4;

  const int tid = threadIdx.x;
  const int wc = tid >> 6;
  const int l = tid & 63;
  const int l4 = l & 15;
  const int hi4 = l >> 4;
  const size_t row0 = (size_t)blockIdx.x * 64;
  const int b = blockIdx.x >> 3;

  pcs[tid] = pc[(size_t)b * 512 + tid];
  pcs[tid + 256] = pc[(size_t)b * 512 + 256 + tid];

  // ---- stage hs -> rowbuf[row][512..768), bf16, swizzled ----
  {
    const float4* hsv = (const float4*)(hs + row0 * 128);
#pragma unroll
    for (int it = 0; it < 8; ++it) {
      int idx = it * 256 + tid;   // 2048 float4 = 64 rows x 32
      int r = idx >> 5, c4 = idx & 31;
      float4 v = hsv[idx];
      bf16x4 hb;
      hb[0] = (__bf16)v.x; hb[1] = (__bf16)v.y;
      hb[2] = (__bf16)v.z; hb[3] = (__bf16)v.w;
      int byte = (r * 768 + 512 + c4 * 8) ^ ((r & 7) << 4);
      *(uint2*)(rowbuf + byte) = __builtin_bit_cast(uint2, hb);
    }
  }
  // ---- stage pos -> rowbuf[row][0..64), bf16, pre-swizzled 16B chunks ----
  if (tid < 64) {
    int row = tid;
    float c = coords[row0 + row];
    __bf16 pv[32];
    pv[0] = (__bf16)c;
    pv[1] = (__bf16)0.0f;  // sin(0*c)
    pv[9] = (__bf16)1.0f;  // cos(0*c)
#pragma unroll
    for (int f = 1; f < 8; ++f) {
      float s, co;
      __sincosf(1.25f * (float)f * c, &s, &co);
      pv[1 + f] = (__bf16)s;
      pv[9 + f] = (__bf16)co;
    }
#pragma unroll
    for (int k = 17; k < 32; ++k) pv[k] = (__bf16)0.0f;
    int base = row * 768, swzp = (row & 7) << 4;
#pragma unroll
    for (int s = 0; s < 4; ++s)
      *(uint4*)(rowbuf + ((base + s * 16) ^ swzp)) = *(const uint4*)&pv[s * 8];
  }

  // per-mt LDS addressing (row&7 == l4&7 since mt*16 ≡ 0 mod 8)
  const int swzU = (l4 & 7) << 4;
  int addrU[4];
#pragma unroll
  for (int mt = 0; mt < 4; ++mt)
    addrU[mt] = (mt * 16 + l4) * 768 + hi4 * 16;

  const uint4* Bb0 = (const uint4*)WT0p;
  const uint4* Bb1 = (const uint4*)WT1p;

  // prefetch GEMM0 step 0 (ks=1) weight frags before the staging barrier
  uint4 wp[4];
#pragma unroll
  for (int i = 0; i < 4; ++i) wp[i] = Bb0[(1 * 16 + wc * 4 + i) * 64 + l];

  __syncthreads();

  f32x4 acc[4][4];
#pragma unroll
  for (int mt = 0; mt < 4; ++mt)
#pragma unroll
    for (int i = 0; i < 4; ++i) acc[mt][i] = (f32x4){0.f, 0.f, 0.f, 0.f};

  // ---------------- GEMM0: K=160, k-order {1,2,3,4,0}, W double-buffered ----------------
#pragma unroll
  for (int kk = 0; kk < 5; ++kk) {
    const int ks = (kk < 4) ? (kk + 1) : 0;
    bf16x8 w[4];
#pragma unroll
    for (int i = 0; i < 4; ++i) w[i] = __builtin_bit_cast(bf16x8, wp[i]);
    if (kk < 4) {
      const int ksn = (kk < 3) ? (kk + 2) : 0;
#pragma unroll
      for (int i = 0; i < 4; ++i) wp[i] = Bb0[(ksn * 16 + wc * 4 + i) * 64 + l];
    }
#pragma unroll
    for (int mt = 0; mt < 4; ++mt) {
      bf16x8 u;
      int off = (ks == 0) ? addrU[mt] : (addrU[mt] + 512 + (ks - 1) * 64);
      __builtin_memcpy(&u, rowbuf + (off ^ swzU), 16);
      __builtin_amdgcn_s_setprio(1);
#pragma unroll
      for (int i = 0; i < 4; ++i)
        acc[mt][i] = __builtin_amdgcn_mfma_f32_16x16x32_bf16(w[i], u, acc[mt][i], 0, 0, 0);
      __builtin_amdgcn_s_setprio(0);
    }
  }

  // prefetch GEMM1 step 0 weights; they land during epilogue0 + barriers
#pragma unroll
  for (int i = 0; i < 4; ++i) wp[i] = Bb1[(wc * 4 + i) * 64 + l];

  __syncthreads();  // all pos reads done before x0 overwrites [0,512)

  // ---- epilogue0: relu(acc + pc0) -> x0 bf16, packed b64 writes ----
#pragma unroll
  for (int i = 0; i < 4; ++i) {
    int n0 = (wc * 4 + i) * 16 + hi4 * 4;
    float4 p4 = *(const float4*)&pcs[n0];
#pragma unroll
    for (int mt = 0; mt < 4; ++mt) {
      int t = mt * 16 + l4;
      bf16x4 hv;
      hv[0] = (__bf16)fmaxf(acc[mt][i][0] + p4.x, 0.f);
      hv[1] = (__bf16)fmaxf(acc[mt][i][1] + p4.y, 0.f);
      hv[2] = (__bf16)fmaxf(acc[mt][i][2] + p4.z, 0.f);
      hv[3] = (__bf16)fmaxf(acc[mt][i][3] + p4.w, 0.f);
      int byte = (t * 768 + n0 * 2) ^ ((t & 7) << 4);
      *(uint2*)(rowbuf + byte) = __builtin_bit_cast(uint2, hv);
    }
  }
  __syncthreads();

#pragma unroll
  for (int mt = 0; mt < 4; ++mt)
#pragma unroll
    for (int i = 0; i < 4; ++i) acc[mt][i] = (f32x4){0.f, 0.f, 0.f, 0.f};

  // ---------------- GEMM1: K=384 (x0 [0,512) then hs [512,768)), W double-buffered ----------------
#pragma unroll
  for (int ks = 0; ks < 12; ++ks) {
    bf16x8 w[4];
#pragma unroll
    for (int i = 0; i < 4; ++i) w[i] = __builtin_bit_cast(bf16x8, wp[i]);
    if (ks < 11) {
#pragma unroll
      for (int i = 0; i < 4; ++i) wp[i] = Bb1[((ks + 1) * 16 + wc * 4 + i) * 64 + l];
    }
#pragma unroll
    for (int mt = 0; mt < 4; ++mt) {
      bf16x8 u;
      __builtin_memcpy(&u, rowbuf + ((addrU[mt] + ks * 64) ^ swzU), 16);
      __builtin_amdgcn_s_setprio(1);
#pragma unroll
      for (int i = 0; i < 4; ++i)
        acc[mt][i] = __builtin_amdgcn_mfma_f32_16x16x32_bf16(w[i], u, acc[mt][i], 0, 0, 0);
      __builtin_amdgcn_s_setprio(0);
    }
  }

  // ---- epilogue1: relu(acc + pc1) . Wo; reduce 16 n per lane + 2 shfl -> psum ----
  {
    float4 p4[4], w4[4];
#pragma unroll
    for (int i = 0; i < 4; ++i) {
      int n0 = (wc * 4 + i) * 16 + hi4 * 4;
      p4[i] = *(const float4*)&pcs[256 + n0];
      w4[i] = ((const float4*)Wo)[(wc * 4 + i) * 4 + hi4];
    }
#pragma unroll
    for (int mt = 0; mt < 4; ++mt) {
      float s = 0.f;
#pragma unroll
      for (int i = 0; i < 4; ++i) {
        s += fmaxf(acc[mt][i][0] + p4[i].x, 0.f) * w4[i].x;
        s += fmaxf(acc[mt][i][1] + p4[i].y, 0.f) * w4[i].y;
        s += fmaxf(acc[mt][i][2] + p4[i].z, 0.f) * w4[i].z;
        s += fmaxf(acc[mt][i][3] + p4[i].w, 0.f) * w4[i].w;
      }
      s += __shfl_xor(s, 16);
      s += __shfl_xor(s, 32);
      if (hi4 == 0) psum[wc * 64 + mt * 16 + l4] = s;
    }
  }
  __syncthreads();
  if (tid < 64) {
    float s = bo[0] + psum[tid] + psum[64 + tid] + psum[128 + tid] + psum[192 + tid];
    out[row0 + tid] = s;
  }
}

extern "C" void kernel_launch(void* const* d_in, const int* in_sizes, int n_in,
                              void* d_out, int out_size, void* d_ws, size_t ws_size,
                              hipStream_t stream) {
  (void)in_sizes; (void)n_in; (void)out_size; (void)ws_size;
  const float* coords    = (const float*)d_in[0];
  const float* code      = (const float*)d_in[1];
  const float* hs        = (const float*)d_in[2];
  const float* x_statics = (const float*)d_in[3];
  const int*   dir_idx   = (const int*)d_in[4];
  const float* W_mod     = (const float*)d_in[5];
  const float* b_mod     = (const float*)d_in[6];
  const float* W0        = (const float*)d_in[7];
  const float* b0        = (const float*)d_in[8];
  const float* W1        = (const float*)d_in[9];
  const float* b1        = (const float*)d_in[10];
  const float* Wo        = (const float*)d_in[11];
  const float* bo        = (const float*)d_in[12];
  const float* Bmat      = (const float*)d_in[13];
  const float* Ws1       = (const float*)d_in[14];
  const float* bs1       = (const float*)d_in[15];
  const float* Ws2       = (const float*)d_in[16];
  const float* bs2       = (const float*)d_in[17];
  const float* dir_emb   = (const float*)d_in[18];
  float* out = (float*)d_out;
  float* wsf = (float*)d_ws;

  float*    WmT  = wsf + WMT_OFF;
  float*    pc   = wsf + PC_OFF;
  ushort_t* WT0p = (ushort_t*)(wsf + WT0P_OFF);
  ushort_t* WT1p = (ushort_t*)(wsf + WT1P_OFF);

  hipLaunchKernelGGL(pack_mfma_k, dim3(1024), dim3(256), 0, stream,
                     W0, W1, W_mod, WmT, WT0p, WT1p);
  hipLaunchKernelGGL(precompute_pc_k, dim3(1024), dim3(512), 0, stream,
                     code, x_statics, dir_idx, WmT, b_mod, b0, b1,
                     Bmat, Ws1, bs1, Ws2, bs2, dir_emb, pc);
  hipLaunchKernelGGL(film_mfma, dim3(8192), dim3(256), 0, stream,
                     coords, hs, pc, WT0p, WT1p, Wo, bo, out);
}